// Round 6
// baseline (289.065 us; speedup 1.0000x reference)
//
#include <hip/hip_runtime.h>

// SharedAdditiveKAN: y = spline(x) @ mix^T + bias
// x: [65536, 512] fp32; bases/slopes: [512, 16] fp32; mix: [512, 512] fp32; bias: [512]
//
// R8: SPLIT the fused kernel. R4/R5/R7 post-mortem: sum-of-pipes (VALU 37us +
// LDS 36us + MFMA 14us) ~= duration (104us) -> pipes run back-to-back, never
// overlapped; every schedule variant inside the fused structure was flat
// because spline-VALU, LDS staging and MFMA all sit in one barrier-locked
// stream. Fix: decouple.
//   k1 spline_kernel: x -> s (bf16, 67 MB in ws). Barrier-free grid-stride
//      stream, 201 MB traffic -> ~35us, VALU ~8us fully hidden by TLP.
//   k2 gemm_kernel: s @ mixb^T -> y. m97-structure: glds-only staging (no
//      VALU phase, no ds_write in loop), double-buffered, 1 syncthreads/kt.
//      s-read L3-hot from k1. ~200 MB -> ~40us.
// ws guard: split needs 67.6 MB; if ws_size is smaller, fall back to the R7
// fused kernel (verified, 104us).

#define DIMK 512
#define DIMN 512

typedef unsigned short u16;
typedef unsigned int u32;
typedef __attribute__((ext_vector_type(8))) __bf16 bf16x8;
typedef __attribute__((ext_vector_type(4))) float f32x4;

__device__ __forceinline__ u32 bf16rne(float f) {
    u32 u = __float_as_uint(f);
    return (u + 0x7fffu + ((u >> 16) & 1u)) >> 16;  // round-to-nearest-even
}

// Prep: convert mix fp32 -> bf16 (ushort bits) into ws, row-major.
__global__ void prep_kernel(const float* __restrict__ mix,
                            u16* __restrict__ mixb) {
    int t = blockIdx.x * 256 + threadIdx.x;             // 65536 threads
    float4 v = reinterpret_cast<const float4*>(mix)[t]; // 4 mix elems each
    ushort4 o;
    o.x = (u16)bf16rne(v.x);
    o.y = (u16)bf16rne(v.y);
    o.z = (u16)bf16rne(v.z);
    o.w = (u16)bf16rne(v.w);
    reinterpret_cast<ushort4*>(mixb)[t] = o;
}

// ---------------- k1: spline stream (x fp32 -> s bf16, row-major) ----------
// Transposed-XOR spline table: word = idx*512 + (dim^idx); bank =
// (dim%32)^idx -> near-conflict-free gathers (verified R7: conflicts at the
// R2 per-spline rate). 33.5M elems, 2048 blocks x 256 thr x 8 iters x 8 elems.
__global__ __launch_bounds__(256) void spline_kernel(
    const float* __restrict__ x, const float* __restrict__ bases,
    const float* __restrict__ slopes, u16* __restrict__ s) {
    __shared__ u32 s_tab[16 * DIMK];  // 32 KB

    const int tid = threadIdx.x;
#pragma unroll
    for (int k = 0; k < 32; k++) {
        int i = tid + k * 256;        // 0..8191 over [D=512][G=16]
        int dim = i >> 4, g = i & 15;
        u32 p = bf16rne(bases[i]) | (bf16rne(slopes[i]) << 16);
        s_tab[g * DIMK + (dim ^ g)] = p;
    }
    __syncthreads();

    const int base = blockIdx.x * 256 + tid;
#pragma unroll 2
    for (int it = 0; it < 8; it++) {
        int i = base + it * 524288;   // 8-elem group index, 0..4194303
        const float4* xp = reinterpret_cast<const float4*>(x) + (size_t)i * 2;
        float4 a = xp[0], b = xp[1];
        const int d0 = (i & 63) << 3; // dim of first elem in group
        float xs[8] = {a.x, a.y, a.z, a.w, b.x, b.y, b.z, b.w};
        bf16x8 r;
#pragma unroll
        for (int j = 0; j < 8; j++) {
            // EXACT replication of reference index math (fp32).
            float xn = fminf(fmaxf((xs[j] + 1.0f) * 0.5f, 0.0f), 0.999999f);
            float tt = xn * 16.0f;
            int idx = (int)tt;        // 0..15 guaranteed
            u32 p = s_tab[idx * DIMK + ((d0 + j) ^ idx)];
            float bs = __uint_as_float(p << 16);
            float sl = __uint_as_float(p & 0xffff0000u);
            float sp = fmaf(sl, tt - (float)idx, bs);
            r[j] = (__bf16)sp;        // RNE
        }
        reinterpret_cast<bf16x8*>(s)[i] = r;
    }
}

// ---------------- k2: GEMM y = s @ mixb^T + bias ---------------------------
// BM=128 x BN=256, BK=32, 512 thr = 8 waves (4m x 2n), wave 32x128,
// mfma_f32_16x16x32_bf16, acc[2][8]. glds-only staging, dbuf, 1 sync/kt.
__global__ __launch_bounds__(512, 4) void gemm_kernel(
    const u16* __restrict__ s, const u16* __restrict__ mixb,
    const float* __restrict__ bias, float* __restrict__ y) {
    // XOR-swizzled tiles: row r, k-chunk c (16B) at chunk (r<<2)|(c^((r>>1)&3))
    __shared__ __align__(16) u16 sA[2][128 * 32];  // 16 KB
    __shared__ __align__(16) u16 sB[2][256 * 32];  // 32 KB -> 48 KB total

    const int tid = threadIdx.x;
    const int lane = tid & 63;
    const int wid = tid >> 6;
    const int quad = lane >> 4;
    const int l15 = lane & 15;
    const int wave_m = wid >> 1;    // 0..3
    const int wave_n = wid & 1;     // 0..1
    // XCD-chunked swizzle (1024 % 8 == 0 -> bijective); n-pairs share s rows.
    const int swz = (blockIdx.x & 7) * 128 + (blockIdx.x >> 3);
    const int m0 = (swz >> 1) * 128;
    const int n0 = (swz & 1) * 256;

    auto stage = [&](int q, int kt) {
        {   // A: 128 rows, 8 groups of 16 -> 1 glds per wave
            int r = wid * 16 + (lane >> 2);
            int c = (lane & 3) ^ ((r >> 1) & 3);
            const u16* gsrc = s + (size_t)(m0 + r) * DIMK + kt * 32 + c * 8;
            __builtin_amdgcn_global_load_lds(
                (const __attribute__((address_space(1))) void*)gsrc,
                (__attribute__((address_space(3))) void*)(&sA[q][wid * 512]),
                16, 0, 0);
        }
#pragma unroll
        for (int i = 0; i < 2; i++) {  // B: 256 rows, 16 groups -> 2 per wave
            int grp = wid * 2 + i;
            int n = grp * 16 + (lane >> 2);
            int c = (lane & 3) ^ ((n >> 1) & 3);
            const u16* gsrc = mixb + (size_t)(n0 + n) * DIMK + kt * 32 + c * 8;
            __builtin_amdgcn_global_load_lds(
                (const __attribute__((address_space(1))) void*)gsrc,
                (__attribute__((address_space(3))) void*)(&sB[q][grp * 512]),
                16, 0, 0);
        }
    };

    f32x4 acc[2][8];
#pragma unroll
    for (int i = 0; i < 2; i++)
#pragma unroll
        for (int j = 0; j < 8; j++) acc[i][j] = (f32x4){0.f, 0.f, 0.f, 0.f};

    stage(0, 0);
    __syncthreads();  // buf0 staged (vmcnt(0) drain inside)

    for (int kt = 0; kt < 16; ++kt) {
        const int p = kt & 1;
        const int q = p ^ 1;
        if (kt < 15) stage(q, kt + 1);  // glds for next kt, lands during compute

        const u16* sAc = &sA[p][0];
        const u16* sBc = &sB[p][0];
        bf16x8 afrag[2];
#pragma unroll
        for (int fm = 0; fm < 2; fm++) {
            int m_l = wave_m * 32 + fm * 16 + l15;
            int ci = (m_l << 2) | (quad ^ ((m_l >> 1) & 3));
            afrag[fm] = *reinterpret_cast<const bf16x8*>(&sAc[ci * 8]);
        }
        __builtin_amdgcn_s_setprio(1);
#pragma unroll
        for (int fn = 0; fn < 8; fn++) {
            int n_l = wave_n * 128 + fn * 16 + l15;
            int ci = (n_l << 2) | (quad ^ ((n_l >> 1) & 3));
            bf16x8 bfrag = *reinterpret_cast<const bf16x8*>(&sBc[ci * 8]);
#pragma unroll
            for (int fm = 0; fm < 2; fm++)
                acc[fm][fn] = __builtin_amdgcn_mfma_f32_16x16x32_bf16(
                    afrag[fm], bfrag, acc[fm][fn], 0, 0, 0);
        }
        __builtin_amdgcn_s_setprio(0);

        if (kt < 15) __syncthreads();  // next buffer staged & visible
    }

    // epilogue: C/D layout col=lane&15, row=quad*4+j
#pragma unroll
    for (int fn = 0; fn < 8; fn++) {
        int o = n0 + wave_n * 128 + fn * 16 + l15;
        float bv = bias[o];
#pragma unroll
        for (int fm = 0; fm < 2; fm++) {
            int row = m0 + wave_m * 32 + fm * 16 + quad * 4;
            float* yp = y + (size_t)row * DIMN + o;
#pragma unroll
            for (int j = 0; j < 4; j++)
                yp[(size_t)j * DIMN] = acc[fm][fn][j] + bv;
        }
    }
}

// ---------------- fallback: R7 fused kernel (verified, ~104us) -------------
__global__ __launch_bounds__(512, 4) void kan_fused_kernel(
    const float* __restrict__ x, const float* __restrict__ bases,
    const float* __restrict__ slopes, const u16* __restrict__ mixb,
    const float* __restrict__ bias, float* __restrict__ y) {
    __shared__ u32 s_tab[16 * DIMK];
    __shared__ __align__(16) u16 sA[2][128 * 32];
    __shared__ __align__(16) u16 sB[2][256 * 32];

    const int tid = threadIdx.x;
    const int lane = tid & 63;
    const int wid = tid >> 6;
    const int quad = lane >> 4;
    const int l15 = lane & 15;
    const int wave_m = wid >> 1;
    const int wave_n = wid & 1;
    const int swz = (blockIdx.x & 7) * 128 + (blockIdx.x >> 3);
    const int m0 = (swz >> 1) * 128;
    const int n0 = (swz & 1) * 256;

#pragma unroll
    for (int k = 0; k < 16; k++) {
        int i = tid + k * 512;
        int dim = i >> 4, g = i & 15;
        u32 p = bf16rne(bases[i]) | (bf16rne(slopes[i]) << 16);
        s_tab[g * DIMK + (dim ^ g)] = p;
    }

    const int ar = tid >> 2;
    const int akg = tid & 3;
    const int awchunk = (ar << 2) | (akg ^ ((ar >> 1) & 3));
    const float4* xrow =
        reinterpret_cast<const float4*>(x + (size_t)(m0 + ar) * DIMK) + akg * 2;

    f32x4 acc[2][8];
#pragma unroll
    for (int i = 0; i < 2; i++)
#pragma unroll
        for (int j = 0; j < 8; j++) acc[i][j] = (f32x4){0.f, 0.f, 0.f, 0.f};

    auto stage_a = [&](u16* sAb, float4 a, float4 b, int kt) {
        float xs[8] = {a.x, a.y, a.z, a.w, b.x, b.y, b.z, b.w};
        const int dbase = kt * 32 + akg * 8;
        u32 h[8];
#pragma unroll
        for (int j = 0; j < 8; j++) {
            float xn = fminf(fmaxf((xs[j] + 1.0f) * 0.5f, 0.0f), 0.999999f);
            float tt = xn * 16.0f;
            int idx = (int)tt;
            u32 p = s_tab[idx * DIMK + ((dbase + j) ^ idx)];
            float bs = __uint_as_float(p << 16);
            float sl = __uint_as_float(p & 0xffff0000u);
            float sp = fmaf(sl, tt - (float)idx, bs);
            h[j] = bf16rne(sp);
        }
        int4 pk = make_int4((int)(h[0] | (h[1] << 16)), (int)(h[2] | (h[3] << 16)),
                            (int)(h[4] | (h[5] << 16)), (int)(h[6] | (h[7] << 16)));
        *reinterpret_cast<int4*>(&sAb[awchunk * 8]) = pk;
    };
    auto stage_b = [&](u16* sBb, int kt) {
#pragma unroll
        for (int i = 0; i < 2; i++) {
            int grp = wid * 2 + i;
            int n = grp * 16 + (lane >> 2);
            int c = (lane & 3) ^ ((n >> 1) & 3);
            const u16* gsrc = mixb + (size_t)(n0 + n) * DIMK + kt * 32 + c * 8;
            __builtin_amdgcn_global_load_lds(
                (const __attribute__((address_space(1))) void*)gsrc,
                (__attribute__((address_space(3))) void*)(&sBb[grp * 512]),
                16, 0, 0);
        }
    };

    float4 p0 = xrow[0], p1 = xrow[1];
    __syncthreads();
    stage_b(&sB[0][0], 0);
    float4 xs0a = xrow[8], xs0b = xrow[9];
    stage_a(&sA[0][0], p0, p1, 0);
    __syncthreads();

    for (int kt = 0; kt < 16; ++kt) {
        const int p = kt & 1;
        const int q = p ^ 1;
        const bool do_stage = (kt < 15);

        float4 xna = xs0a, xnb = xs0b;
        if (do_stage) {
            stage_b(&sB[q][0], kt + 1);
            const int ktn = ((kt + 2) & 15) * 8;
            xna = xrow[ktn];
            xnb = xrow[ktn + 1];
            stage_a(&sA[q][0], xs0a, xs0b, kt + 1);
        }

        const u16* sAc = &sA[p][0];
        const u16* sBc = &sB[p][0];
        bf16x8 afrag[2];
#pragma unroll
        for (int fm = 0; fm < 2; fm++) {
            int m_l = wave_m * 32 + fm * 16 + l15;
            int ci = (m_l << 2) | (quad ^ ((m_l >> 1) & 3));
            afrag[fm] = *reinterpret_cast<const bf16x8*>(&sAc[ci * 8]);
        }
#pragma unroll
        for (int fn = 0; fn < 8; fn++) {
            int n_l = wave_n * 128 + fn * 16 + l15;
            int ci = (n_l << 2) | (quad ^ ((n_l >> 1) & 3));
            bf16x8 bfrag = *reinterpret_cast<const bf16x8*>(&sBc[ci * 8]);
#pragma unroll
            for (int fm = 0; fm < 2; fm++)
                acc[fm][fn] = __builtin_amdgcn_mfma_f32_16x16x32_bf16(
                    afrag[fm], bfrag, acc[fm][fn], 0, 0, 0);
        }

        if (do_stage) __syncthreads();
        xs0a = xna;
        xs0b = xnb;
    }

#pragma unroll
    for (int fn = 0; fn < 8; fn++) {
        int o = n0 + wave_n * 128 + fn * 16 + l15;
        float bv = bias[o];
#pragma unroll
        for (int fm = 0; fm < 2; fm++) {
            int row = m0 + wave_m * 32 + fm * 16 + quad * 4;
            float* yp = y + (size_t)row * DIMN + o;
#pragma unroll
            for (int j = 0; j < 4; j++)
                yp[(size_t)j * DIMN] = acc[fm][fn][j] + bv;
        }
    }
}

extern "C" void kernel_launch(void* const* d_in, const int* in_sizes, int n_in,
                              void* d_out, int out_size, void* d_ws, size_t ws_size,
                              hipStream_t stream) {
    const float* x = (const float*)d_in[0];
    const float* bases = (const float*)d_in[1];
    const float* slopes = (const float*)d_in[2];
    const float* mix = (const float*)d_in[3];
    const float* bias = (const float*)d_in[4];
    float* y = (float*)d_out;

    u16* mixb = (u16*)d_ws;                      // 512 KB bf16 mix
    const size_t NEED = 512 * 1024 + (size_t)65536 * 512 * 2;  // +67.1 MB s

    hipLaunchKernelGGL(prep_kernel, dim3(256), dim3(256), 0, stream, mix, mixb);

    if (ws_size >= NEED) {
        u16* sbuf = mixb + 512 * 1024 / 2;       // s right after mixb
        hipLaunchKernelGGL(spline_kernel, dim3(2048), dim3(256), 0, stream,
                           x, bases, slopes, sbuf);
        hipLaunchKernelGGL(gemm_kernel, dim3(1024), dim3(512), 0, stream,
                           sbuf, mixb, bias, y);
    } else {
        hipLaunchKernelGGL(kan_fused_kernel, dim3(1024), dim3(512), 0, stream,
                           x, bases, slopes, mixb, bias, y);
    }
}

// Round 7
// 282.240 us; speedup vs baseline: 1.0242x; 1.0242x over previous
//
#include <hip/hip_runtime.h>

// SharedAdditiveKAN: y = spline(x) @ mix^T + bias
// x: [65536, 512] fp32; bases/slopes: [512, 16] fp32; mix: [512, 512] fp32; bias: [512]
//
// R9: ZERO-BARRIER K-loop via wave-independent tiles. Evidence R0-R8: fused
// kernel flat (~96-108us) under dbuf/occupancy/counted-vmcnt/setprio; all
// pipes <40%; R5's 2 blocks/CU flat => NOT latency-bound; the invariant is
// the per-kt block-wide barrier lockstep (producer and consumer phases
// serialize). R8's two-pass split regressed (+134 MB round trip).
// Fix: remove tile SHARING, so barriers aren't needed at all:
//  - B: one 128-col strip of fragment-linear mixb resident in LDS for the
//    WHOLE kernel (128 KB, staged once by linear global_load_lds w=16;
//    frag reads are stride-1 conflict-free ds_read_b128).
//  - A: spline computed in-register per wave (R3's verified frag math) --
//    no ds_write, no A tile, no staging phase.
//  - LDS = 32 KB table + 128 KB B = 163840 B exactly (AITER attn precedent
//    for 160 KB). 1 block/CU, 8 waves, each wave owns 32 rows x 128 cols
//    and runs kt=0..15 with NO __syncthreads after init.
//  - Grid 4 strips x 256 mbands, XCD-swizzled so the 4 strips of an mband
//    run concurrently on one XCD -> x re-reads (x4) are L2/L3 hits.
// Cost: spline VALU x4 chip-wide (~25-30us, overlappable). All pipes now
// run concurrently; wall ~= max(pipe) instead of sum.

#define DIMK 512
#define DIMN 512

typedef unsigned short u16;
typedef unsigned int u32;
typedef __attribute__((ext_vector_type(8))) __bf16 bf16x8;
typedef __attribute__((ext_vector_type(4))) float f32x4;

__device__ __forceinline__ u32 bf16rne(float f) {
    u32 u = __float_as_uint(f);
    return (u + 0x7fffu + ((u >> 16) & 1u)) >> 16;  // round-to-nearest-even
}

// Prep: mix fp32 [O=512][D=512] -> bf16 in fragment-linear layout (verified
// in R3). Fragment f = (g*16 + kt), element (f*64 + lane)*8 holds
// mix[g*16 + (lane&15)][kt*32 + (lane>>4)*8 .. +8] -- the mfma_16x16x32
// B-operand for column-group g at k-step kt.
__global__ void prep_kernel(const float* __restrict__ mix,
                            u16* __restrict__ mixb) {
    int t = blockIdx.x * 256 + threadIdx.x;  // 32768 threads, 8 elems each
    int lane = t & 63;
    int gk = t >> 6;
    int kt = gk & 15;
    int g = gk >> 4;
    int n = g * 16 + (lane & 15);
    int d = kt * 32 + (lane >> 4) * 8;
    const float4* src = reinterpret_cast<const float4*>(mix + (size_t)n * DIMK + d);
    float4 a = src[0];
    float4 b = src[1];
    ushort4 lo, hi;
    lo.x = (u16)bf16rne(a.x); lo.y = (u16)bf16rne(a.y);
    lo.z = (u16)bf16rne(a.z); lo.w = (u16)bf16rne(a.w);
    hi.x = (u16)bf16rne(b.x); hi.y = (u16)bf16rne(b.y);
    hi.z = (u16)bf16rne(b.z); hi.w = (u16)bf16rne(b.w);
    ushort4* dst = reinterpret_cast<ushort4*>(mixb + (size_t)t * 8);
    dst[0] = lo;
    dst[1] = hi;
}

// 8 splines (one A-fragment) fully in registers. Transposed-XOR table:
// word = idx*512 + (dim^idx) -> bank = (dim%32)^idx: distinct idx ->
// distinct banks, equal idx -> broadcast (verified R7: low conflicts).
__device__ __forceinline__ bf16x8 spline8(float4 a, float4 b,
                                          const u32* tab, int dbase) {
    float xs[8] = {a.x, a.y, a.z, a.w, b.x, b.y, b.z, b.w};
    bf16x8 r;
#pragma unroll
    for (int j = 0; j < 8; j++) {
        // EXACT reference index math (fp32): xn = clip((x+1)*0.5, 0, 0.999999)
        float xn = fminf(fmaxf((xs[j] + 1.0f) * 0.5f, 0.0f), 0.999999f);
        float tt = xn * 16.0f;
        int idx = (int)tt;  // 0..15 guaranteed
        u32 p = tab[idx * DIMK + ((dbase + j) ^ idx)];
        float bs = __uint_as_float(p << 16);
        float sl = __uint_as_float(p & 0xffff0000u);
        float sp = fmaf(sl, tt - (float)idx, bs);
        r[j] = (__bf16)sp;  // RNE
    }
    return r;
}

__global__ __launch_bounds__(512, 2) void kan_kernel(
    const float* __restrict__ x, const float* __restrict__ bases,
    const float* __restrict__ slopes, const u16* __restrict__ mixb,
    const float* __restrict__ bias, float* __restrict__ y) {
    // Single LDS array, carved manually: exactly 163840 B (= 160 KiB max).
    __shared__ __align__(16) u32 smem[40960];
    u32* s_tab = smem;                                   // 32 KB spline table
    u16* sB = reinterpret_cast<u16*>(smem + 8192);       // 128 KB B strip

    const int tid = threadIdx.x;
    const int lane = tid & 63;
    const int wid = tid >> 6;     // 0..7
    const int quad = lane >> 4;   // 0..3
    const int l15 = lane & 15;

    // XCD-chunked swizzle (1024 % 8 == 0 -> bijective). swz orders blocks as
    // (mband, strip) with strip fastest -> the 4 strips of an mband sit in
    // the same XCD chunk (concurrent on one XCD -> x re-reads L2-hit).
    const int swz = (blockIdx.x & 7) * 128 + (blockIdx.x >> 3);
    const int strip = swz & 3;     // 128-col strip of N
    const int mband = swz >> 2;    // 256-row band of M
    const int n0 = strip * 128;
    const int mw = mband * 256 + wid * 32;  // this wave's 32 rows

    // ---- one-time: spline table -> LDS (coalesced fp32 reads) ----
#pragma unroll
    for (int k = 0; k < 16; k++) {
        int i = tid + k * 512;     // 0..8191 over [D=512][G=16]
        int dim = i >> 4, g = i & 15;
        u32 p = bf16rne(bases[i]) | (bf16rne(slopes[i]) << 16);
        s_tab[g * DIMK + (dim ^ g)] = p;
    }

    // ---- one-time: B strip (fragment-linear, 131072 B) -> LDS ----
    // Pure linear copy: glds dest = wave-uniform base + lane*16.
    const u16* bsrc = mixb + (size_t)strip * 65536;  // 8 col-groups x 16 kt
#pragma unroll
    for (int i = 0; i < 16; i++) {
        const u16* gs = bsrc + (size_t)(tid + i * 512) * 8;
        __builtin_amdgcn_global_load_lds(
            (const __attribute__((address_space(1))) void*)gs,
            (__attribute__((address_space(3))) void*)(
                &sB[(size_t)(wid * 64 + i * 512) * 8]),
            16, 0, 0);
    }

    // x pointers: lane reads rows (mw + fm*16 + l15), cols kt*32 + quad*8..+8
    const float4* xp0 = reinterpret_cast<const float4*>(
                            x + (size_t)(mw + l15) * DIMK) + quad * 2;
    const float4* xp1 = xp0 + 16 * (DIMK / 4);  // +16 rows

    f32x4 acc[2][8];
#pragma unroll
    for (int i = 0; i < 2; i++)
#pragma unroll
        for (int j = 0; j < 8; j++) acc[i][j] = (f32x4){0.f, 0.f, 0.f, 0.f};

    // preload x for kt=0
    float4 xa0 = xp0[0], xa1 = xp0[1];
    float4 xb0 = xp1[0], xb1 = xp1[1];

    __syncthreads();  // table + B staged (drains vmcnt+lgkm). LAST barrier.

    // ---- barrier-free K-loop: waves fully independent ----
#pragma unroll 4
    for (int kt = 0; kt < 16; ++kt) {
        // x prefetch for kt+1 (wraps at tail; result unused, memory valid)
        const int ktn = ((kt + 1) & 15) * 8;
        float4 na0 = xp0[ktn], na1 = xp0[ktn + 1];
        float4 nb0 = xp1[ktn], nb1 = xp1[ktn + 1];

        // A fragments: 16 splines in registers
        const int dbase = kt * 32 + quad * 8;
        bf16x8 af0 = spline8(xa0, xa1, s_tab, dbase);
        bf16x8 af1 = spline8(xb0, xb1, s_tab, dbase);

        __builtin_amdgcn_s_setprio(1);
#pragma unroll
        for (int fn = 0; fn < 8; fn++) {
            // frag (fn, kt): 64 lanes read 1024 contiguous bytes -> no conflict
            bf16x8 bfrag = *reinterpret_cast<const bf16x8*>(
                &sB[(size_t)((fn * 16 + kt) * 64 + lane) * 8]);
            acc[0][fn] = __builtin_amdgcn_mfma_f32_16x16x32_bf16(
                af0, bfrag, acc[0][fn], 0, 0, 0);
            acc[1][fn] = __builtin_amdgcn_mfma_f32_16x16x32_bf16(
                af1, bfrag, acc[1][fn], 0, 0, 0);
        }
        __builtin_amdgcn_s_setprio(0);

        xa0 = na0; xa1 = na1; xb0 = nb0; xb1 = nb1;
    }

    // ---- epilogue: C/D layout col=lane&15, row=quad*4+j (verified R3) ----
#pragma unroll
    for (int fn = 0; fn < 8; fn++) {
        int o = n0 + fn * 16 + l15;
        float bv = bias[o];
#pragma unroll
        for (int fm = 0; fm < 2; fm++) {
            int row = mw + fm * 16 + quad * 4;
            float* yp = y + (size_t)row * DIMN + o;
#pragma unroll
            for (int j = 0; j < 4; j++)
                yp[(size_t)j * DIMN] = acc[fm][fn][j] + bv;
        }
    }
}

extern "C" void kernel_launch(void* const* d_in, const int* in_sizes, int n_in,
                              void* d_out, int out_size, void* d_ws, size_t ws_size,
                              hipStream_t stream) {
    const float* x = (const float*)d_in[0];
    const float* bases = (const float*)d_in[1];
    const float* slopes = (const float*)d_in[2];
    const float* mix = (const float*)d_in[3];
    const float* bias = (const float*)d_in[4];
    float* y = (float*)d_out;

    u16* mixb = (u16*)d_ws;  // 512 KB bf16 mix, fragment-linear

    hipLaunchKernelGGL(prep_kernel, dim3(128), dim3(256), 0, stream, mix, mixb);
    hipLaunchKernelGGL(kan_kernel, dim3(1024), dim3(512), 0, stream,
                       x, bases, slopes, mixb, bias, y);
}